// Round 2
// baseline (552.672 us; speedup 1.0000x reference)
//
#include <hip/hip_runtime.h>
#include <hip/hip_bf16.h>

#define B_ 4
#define T_ 8
#define N_ 4096
#define F_ 32
#define C_ 32
#define H_ 64
#define BT_ (B_*T_)
#define ROWS_ (B_*N_)
#define CAP_ 128
#define EPS_ 1e-5f
#define NELEM_ (B_*T_*N_*F_)

// ---- workspace layout (float offsets) ----
#define WS_BNSUM 0                       // 64 floats: sum[32], sumsq[32]
#define WS_WX    64                      // 32*192
#define WS_U     (WS_WX + 32*192)        // 192
#define WS_V     (WS_U + 192)            // 192
#define WS_ROWSUM (WS_V + 192)           // 4096
#define WS_DEG   (WS_ROWSUM + 4096)      // 4096 (int)
#define WS_IDX   (WS_DEG + 4096)         // 4096*CAP_ (int)
#define WS_VAL   (WS_IDX + 4096*CAP_)    // 4096*CAP_
#define WS_XA    (WS_VAL + 4096*CAP_)    // BT_*N_*F_  (aggregated raw x)

__device__ inline float lanebc(float v, int l) {
  return __int_as_float(__builtin_amdgcn_readlane(__float_as_int(v), l));
}

// ---- K1: batchnorm stats (sum, sumsq per channel) ----
__global__ void __launch_bounds__(256)
k_bn_stats(const float* __restrict__ x, float* __restrict__ ws) {
  int tid = blockIdx.x * 256 + threadIdx.x;
  int stride = gridDim.x * 256;            // multiple of 32 -> f fixed per thread
  float s = 0.f, s2 = 0.f;
  for (int i = tid; i < NELEM_; i += stride) { float v = x[i]; s += v; s2 += v * v; }
  __shared__ float ls[256], ls2[256];
  ls[threadIdx.x] = s; ls2[threadIdx.x] = s2;
  __syncthreads();
  if (threadIdx.x < 32) {
    float a = 0.f, b = 0.f;
    for (int q = threadIdx.x; q < 256; q += 32) { a += ls[q]; b += ls2[q]; }
    atomicAdd(&ws[WS_BNSUM + threadIdx.x], a);
    atomicAdd(&ws[WS_BNSUM + 32 + threadIdx.x], b);
  }
}

// ---- K2: fold BN + W_gcn + W_ih into Wx[32][192], u[192], v[192] ----
__global__ void __launch_bounds__(256)
k_fold(const float* __restrict__ gamma, const float* __restrict__ beta,
       const float* __restrict__ Wg, const float* __restrict__ bg,
       const float* __restrict__ Wih, const float* __restrict__ bih,
       float* __restrict__ ws) {
  __shared__ float scale_s[32], shift_s[32], p_s[32];
  int t = threadIdx.x;
  if (t < 32) {
    float cnt = (float)(B_ * T_ * N_);
    float mean = ws[WS_BNSUM + t] / cnt;
    float var = ws[WS_BNSUM + 32 + t] / cnt - mean * mean;
    float sc = gamma[t] * rsqrtf(var + EPS_);
    scale_s[t] = sc;
    shift_s[t] = beta[t] - mean * sc;
  }
  __syncthreads();
  if (t < 32) {  // p[c] = sum_f shift[f] * Wg[f][c]
    float acc = 0.f;
    for (int f = 0; f < 32; f++) acc += shift_s[f] * Wg[f * 32 + t];
    p_s[t] = acc;
  }
  __syncthreads();
  for (int e = t; e < 32 * 192; e += 256) {   // Wx[f][j] = scale[f]*sum_c Wg[f][c]*Wih[c][j]
    int f = e / 192, j = e % 192;
    float acc = 0.f;
    for (int c = 0; c < 32; c++) acc += Wg[f * 32 + c] * Wih[c * 192 + j];
    ws[WS_WX + e] = scale_s[f] * acc;
  }
  for (int j = t; j < 192; j += 256) {
    float au = 0.f, av = 0.f;
    for (int c = 0; c < 32; c++) { au += p_s[c] * Wih[c * 192 + j]; av += bg[c] * Wih[c * 192 + j]; }
    ws[WS_U + j] = au;
    ws[WS_V + j] = av + bih[j];
  }
}

// ---- K3: build fixed-capacity CSR from dense adj_norm ----
__global__ void __launch_bounds__(256)
k_csr(const float* __restrict__ A, float* __restrict__ ws) {
  int m = blockIdx.x;
  __shared__ int cnt;
  __shared__ float rsum[256];
  if (threadIdx.x == 0) cnt = 0;
  __syncthreads();
  int* deg = (int*)&ws[WS_DEG];
  int* idx = (int*)&ws[WS_IDX];
  float* val = &ws[WS_VAL];
  float lsum = 0.f;
  for (int n = threadIdx.x; n < N_; n += 256) {
    float a = A[(size_t)m * N_ + n];
    if (a != 0.0f) {
      int p = atomicAdd(&cnt, 1);
      if (p < CAP_) { idx[m * CAP_ + p] = n; val[m * CAP_ + p] = a; }
      lsum += a;
    }
  }
  rsum[threadIdx.x] = lsum;
  __syncthreads();
  for (int s = 128; s > 0; s >>= 1) {
    if (threadIdx.x < s) rsum[threadIdx.x] += rsum[threadIdx.x + s];
    __syncthreads();
  }
  if (threadIdx.x == 0) { deg[m] = min(cnt, CAP_); ws[WS_ROWSUM + m] = rsum[0]; }
}

// ---- K4: sparse aggregation  xa[bt][m][f] = sum_k val*x[bt][idx][f] ----
// bt-outer grid order for L2 locality on x[bt] slice (512 KB per bt).
__global__ void __launch_bounds__(256)
k_agg(const float* __restrict__ x, float* __restrict__ ws) {
  int bt = blockIdx.x >> 9;
  int mg = blockIdx.x & 511;
  int mi = threadIdx.x >> 5, f = threadIdx.x & 31;
  int m = mg * 8 + mi;
  const int* deg = (const int*)&ws[WS_DEG];
  const int* idx = (const int*)&ws[WS_IDX];
  const float* val = &ws[WS_VAL];
  const float* xb = x + (size_t)bt * N_ * F_;
  int d = deg[m];
  float acc = 0.f;
  for (int k = 0; k < d; k++) {
    int n = idx[m * CAP_ + k];
    float a = val[m * CAP_ + k];
    acc += a * xb[n * F_ + f];
  }
  ws[WS_XA + (size_t)bt * N_ * F_ + m * F_ + f] = acc;
}

// ---- K5: fused gi-projection + GRU scan + dense head ----
// wave = 64 j-lanes, owns 8 rows; h[row][j] lives in lane j's register.
__global__ void __launch_bounds__(256, 2)
k_gru(const float* __restrict__ Whh, const float* __restrict__ bhh,
      const float* __restrict__ Wd, const float* __restrict__ bd,
      const float* __restrict__ ws, float* __restrict__ out) {
  __shared__ float Wr[64 * 64], Wz[64 * 64], Wn[64 * 64];   // [k][j]
  __shared__ float Xr[32 * 64], Xz[32 * 64], Xn[32 * 64];   // [f][j]
  int tid = threadIdx.x;
  for (int e = tid; e < 64 * 64; e += 256) {
    int k = e >> 6, j = e & 63;
    Wr[e] = Whh[k * 192 + j];
    Wz[e] = Whh[k * 192 + 64 + j];
    Wn[e] = Whh[k * 192 + 128 + j];
  }
  const float* wx = ws + WS_WX;
  for (int e = tid; e < 32 * 64; e += 256) {
    int f = e >> 6, j = e & 63;
    Xr[e] = wx[f * 192 + j];
    Xz[e] = wx[f * 192 + 64 + j];
    Xn[e] = wx[f * 192 + 128 + j];
  }
  __syncthreads();

  int g = tid >> 6, j = tid & 63;
  int base = blockIdx.x * 32 + g * 8;     // first of this wave's 8 rows
  int b = base >> 12;                     // N_=4096
  int nbase = base & (N_ - 1);
  float u_r = ws[WS_U + j], u_z = ws[WS_U + 64 + j], u_n = ws[WS_U + 128 + j];
  float v_r = ws[WS_V + j], v_z = ws[WS_V + 64 + j], v_n = ws[WS_V + 128 + j];
  float bh_r = bhh[j], bh_z = bhh[64 + j], bh_n = bhh[128 + j];
  float wd = Wd[j];
  float bdv = bd[0];
  float rs[8], h[8];
#pragma unroll
  for (int s = 0; s < 8; s++) { rs[s] = ws[WS_ROWSUM + nbase + s]; h[s] = 0.0f; }

  for (int t = 0; t < T_; t++) {
    int bt = b * T_ + t;
    const float* xab = ws + WS_XA + (size_t)bt * N_ * F_;
    float xar[8];
#pragma unroll
    for (int s = 0; s < 8; s++) xar[s] = xab[(nbase + s) * F_ + (j & 31)];

    float ar[8], az[8], agi[8], agh[8];
#pragma unroll
    for (int s = 0; s < 8; s++) { ar[s] = 0.f; az[s] = 0.f; agi[s] = 0.f; agh[s] = 0.f; }

#pragma unroll
    for (int f = 0; f < 32; f++) {          // gi part: xa @ Wx
      float wxr = Xr[f * 64 + j], wxz = Xz[f * 64 + j], wxn = Xn[f * 64 + j];
#pragma unroll
      for (int s = 0; s < 8; s++) {
        float xv = lanebc(xar[s], f);
        ar[s] += xv * wxr; az[s] += xv * wxz; agi[s] += xv * wxn;
      }
    }
#pragma unroll 16
    for (int k = 0; k < 64; k++) {          // gh part: h @ W_hh
      float wr_ = Wr[k * 64 + j], wz_ = Wz[k * 64 + j], wn_ = Wn[k * 64 + j];
#pragma unroll
      for (int s = 0; s < 8; s++) {
        float hv = lanebc(h[s], k);
        ar[s] += hv * wr_; az[s] += hv * wz_; agh[s] += hv * wn_;
      }
    }
#pragma unroll
    for (int s = 0; s < 8; s++) {
      float pre_r = ar[s] + rs[s] * u_r + v_r + bh_r;
      float pre_z = az[s] + rs[s] * u_z + v_z + bh_z;
      float r = 1.0f / (1.0f + __expf(-pre_r));
      float z = 1.0f / (1.0f + __expf(-pre_z));
      float nn = tanhf(agi[s] + rs[s] * u_n + v_n + r * (agh[s] + bh_n));
      h[s] = (1.0f - z) * nn + z * h[s];
    }
#pragma unroll
    for (int s = 0; s < 8; s++) {           // out = h @ W_dense + b_dense
      float o = h[s] * wd;
#pragma unroll
      for (int off = 32; off > 0; off >>= 1) o += __shfl_xor(o, off, 64);
      if (j == 0) out[(size_t)bt * N_ + nbase + s] = o + bdv;
    }
  }
}

extern "C" void kernel_launch(void* const* d_in, const int* in_sizes, int n_in,
                              void* d_out, int out_size, void* d_ws, size_t ws_size,
                              hipStream_t stream) {
  const float* x     = (const float*)d_in[0];
  const float* adj   = (const float*)d_in[1];
  const float* gamma = (const float*)d_in[2];
  const float* beta  = (const float*)d_in[3];
  const float* Wg    = (const float*)d_in[4];
  const float* bg    = (const float*)d_in[5];
  const float* Wih   = (const float*)d_in[6];
  const float* Whh   = (const float*)d_in[7];
  const float* bih   = (const float*)d_in[8];
  const float* bhh   = (const float*)d_in[9];
  const float* Wd    = (const float*)d_in[10];
  const float* bd    = (const float*)d_in[11];
  float* ws = (float*)d_ws;
  float* out = (float*)d_out;

  hipMemsetAsync(ws, 0, 64 * sizeof(float), stream);           // zero bnsum only
  k_bn_stats<<<1024, 256, 0, stream>>>(x, ws);
  k_fold<<<1, 256, 0, stream>>>(gamma, beta, Wg, bg, Wih, bih, ws);
  k_csr<<<N_, 256, 0, stream>>>(adj, ws);
  k_agg<<<BT_ * 512, 256, 0, stream>>>(x, ws);
  k_gru<<<ROWS_ / 32, 256, 0, stream>>>(Whh, bhh, Wd, bd, ws, out);
}

// Round 3
// 352.233 us; speedup vs baseline: 1.5691x; 1.5691x over previous
//
#include <hip/hip_runtime.h>
#include <hip/hip_bf16.h>

#define B_ 4
#define T_ 8
#define N_ 4096
#define F_ 32
#define C_ 32
#define H_ 64
#define BT_ (B_*T_)
#define ROWS_ (B_*N_)
#define CAP_ 128
#define EPS_ 1e-5f
#define NELEM_ (B_*T_*N_*F_)

// ---- workspace layout (float offsets) ----
#define WS_BNSUM 0                        // 64 floats: sum[32], sumsq[32]
#define WS_WX    64                       // 32*192
#define WS_U     (WS_WX + 32*192)         // 192
#define WS_V     (WS_U + 192)             // 192
#define WS_ROWSUM (WS_V + 192)            // 4096
#define WS_DEG   (WS_ROWSUM + 4096)       // 4096 (int)
#define WS_PAIR  (WS_DEG + 4096)          // 4096*CAP_*2 floats, (idx_bits, val) pairs
#define WS_XA    (WS_PAIR + 4096*CAP_*2)  // BT_*N_*F_  (aggregated raw x)

__device__ inline float lanebc(float v, int l) {
  return __int_as_float(__builtin_amdgcn_readlane(__float_as_int(v), l));
}

// ---- K1: batchnorm stats (sum, sumsq per channel) ----
__global__ void __launch_bounds__(256)
k_bn_stats(const float* __restrict__ x, float* __restrict__ ws) {
  int tid = blockIdx.x * 256 + threadIdx.x;
  int stride = gridDim.x * 256;            // multiple of 32 -> f fixed per thread
  float s = 0.f, s2 = 0.f;
  for (int i = tid; i < NELEM_; i += stride) { float v = x[i]; s += v; s2 += v * v; }
  __shared__ float ls[256], ls2[256];
  ls[threadIdx.x] = s; ls2[threadIdx.x] = s2;
  __syncthreads();
  if (threadIdx.x < 32) {
    float a = 0.f, b = 0.f;
    for (int q = threadIdx.x; q < 256; q += 32) { a += ls[q]; b += ls2[q]; }
    atomicAdd(&ws[WS_BNSUM + threadIdx.x], a);
    atomicAdd(&ws[WS_BNSUM + 32 + threadIdx.x], b);
  }
}

// ---- K2: fold BN + W_gcn + W_ih into Wx[32][192], u[192], v[192] ----
__global__ void __launch_bounds__(256)
k_fold(const float* __restrict__ gamma, const float* __restrict__ beta,
       const float* __restrict__ Wg, const float* __restrict__ bg,
       const float* __restrict__ Wih, const float* __restrict__ bih,
       float* __restrict__ ws) {
  __shared__ float scale_s[32], shift_s[32], p_s[32];
  int t = threadIdx.x;
  if (t < 32) {
    float cnt = (float)(B_ * T_ * N_);
    float mean = ws[WS_BNSUM + t] / cnt;
    float var = ws[WS_BNSUM + 32 + t] / cnt - mean * mean;
    float sc = gamma[t] * rsqrtf(var + EPS_);
    scale_s[t] = sc;
    shift_s[t] = beta[t] - mean * sc;
  }
  __syncthreads();
  if (t < 32) {  // p[c] = sum_f shift[f] * Wg[f][c]
    float acc = 0.f;
    for (int f = 0; f < 32; f++) acc += shift_s[f] * Wg[f * 32 + t];
    p_s[t] = acc;
  }
  __syncthreads();
  for (int e = t; e < 32 * 192; e += 256) {   // Wx[f][j] = scale[f]*sum_c Wg[f][c]*Wih[c][j]
    int f = e / 192, j = e % 192;
    float acc = 0.f;
    for (int c = 0; c < 32; c++) acc += Wg[f * 32 + c] * Wih[c * 192 + j];
    ws[WS_WX + e] = scale_s[f] * acc;
  }
  for (int j = t; j < 192; j += 256) {
    float au = 0.f, av = 0.f;
    for (int c = 0; c < 32; c++) { au += p_s[c] * Wih[c * 192 + j]; av += bg[c] * Wih[c * 192 + j]; }
    ws[WS_U + j] = au;
    ws[WS_V + j] = av + bih[j];
  }
}

// ---- K3: build fixed-capacity CSR (interleaved idx/val pairs) ----
__global__ void __launch_bounds__(256)
k_csr(const float* __restrict__ A, float* __restrict__ ws) {
  int m = blockIdx.x;
  __shared__ int cnt;
  __shared__ float rsum[256];
  if (threadIdx.x == 0) cnt = 0;
  __syncthreads();
  int* deg = (int*)&ws[WS_DEG];
  float2* pair = (float2*)&ws[WS_PAIR];
  float lsum = 0.f;
  for (int n = threadIdx.x; n < N_; n += 256) {
    float a = A[(size_t)m * N_ + n];
    if (a != 0.0f) {
      int p = atomicAdd(&cnt, 1);
      if (p < CAP_) pair[(size_t)m * CAP_ + p] = make_float2(__int_as_float(n), a);
      lsum += a;
    }
  }
  rsum[threadIdx.x] = lsum;
  __syncthreads();                     // cnt final here
  int c = cnt;
  for (int p = c + threadIdx.x; p < 64; p += 256)   // zero-fill so k_agg can run un-predicated
    pair[(size_t)m * CAP_ + p] = make_float2(__int_as_float(0), 0.0f);
  for (int s = 128; s > 0; s >>= 1) {
    if (threadIdx.x < s) rsum[threadIdx.x] += rsum[threadIdx.x + s];
    __syncthreads();
  }
  if (threadIdx.x == 0) { deg[m] = min(c, CAP_); ws[WS_ROWSUM + m] = rsum[0]; }
}

// ---- K4: sparse aggregation  xa[bt][m][f] = sum_k val*x[bt][idx][f] ----
// 8 rows/block; (idx,val) pairs staged to LDS coalesced; uniform trip count.
__global__ void __launch_bounds__(256)
k_agg(const float* __restrict__ x, float* __restrict__ ws) {
  int bt = blockIdx.x >> 9;
  int mg = blockIdx.x & 511;
  int g = threadIdx.x >> 5, f = threadIdx.x & 31;
  int m = mg * 8 + g;
  const int* deg = (const int*)&ws[WS_DEG];
  const float2* pair = (const float2*)&ws[WS_PAIR];
  __shared__ float2 pl[8 * 64];
  for (int q = threadIdx.x; q < 512; q += 256) {
    int r = q >> 6, sl = q & 63;
    pl[q] = pair[(size_t)(mg * 8 + r) * CAP_ + sl];
  }
  __syncthreads();
  int d = deg[m];
  int dm = min(d, 64);
  int bound = max(dm, __shfl_xor(dm, 32, 64));   // wave-uniform; zero-fill makes extras safe
  const float* xb = x + (size_t)bt * N_ * F_;
  float acc = 0.f;
#pragma unroll 4
  for (int k = 0; k < bound; k++) {
    float2 p = pl[g * 64 + k];
    int n = __float_as_int(p.x);
    acc += p.y * xb[n * F_ + f];
  }
  if (d > 64) {                                  // statistically never (avg deg ~32)
    for (int k = 64; k < d; k++) {
      float2 p = pair[(size_t)m * CAP_ + k];
      acc += p.y * xb[__float_as_int(p.x) * F_ + f];
    }
  }
  ws[WS_XA + (size_t)bt * N_ * F_ + m * F_ + f] = acc;
}

// ---- K5: fused gi-projection + GRU scan + dense head ----
// wave = 64 j-lanes, owns 4 rows; h[row][j] in lane j's register. 16 accums -> no spill.
__global__ void __launch_bounds__(256, 2)
k_gru(const float* __restrict__ Whh, const float* __restrict__ bhh,
      const float* __restrict__ Wd, const float* __restrict__ bd,
      const float* __restrict__ ws, float* __restrict__ out) {
  __shared__ float Wr[64 * 64], Wz[64 * 64], Wn[64 * 64];   // [k][j]
  __shared__ float Xr[32 * 64], Xz[32 * 64], Xn[32 * 64];   // [f][j]
  int tid = threadIdx.x;
  for (int e = tid; e < 64 * 64; e += 256) {
    int k = e >> 6, j = e & 63;
    Wr[e] = Whh[k * 192 + j];
    Wz[e] = Whh[k * 192 + 64 + j];
    Wn[e] = Whh[k * 192 + 128 + j];
  }
  const float* wx = ws + WS_WX;
  for (int e = tid; e < 32 * 64; e += 256) {
    int f = e >> 6, j = e & 63;
    Xr[e] = wx[f * 192 + j];
    Xz[e] = wx[f * 192 + 64 + j];
    Xn[e] = wx[f * 192 + 128 + j];
  }
  __syncthreads();

  int g = tid >> 6, j = tid & 63;
  int base = blockIdx.x * 16 + g * 4;     // first of this wave's 4 rows
  int b = base >> 12;                     // N_=4096
  int nbase = base & (N_ - 1);
  float u_r = ws[WS_U + j], u_z = ws[WS_U + 64 + j], u_n = ws[WS_U + 128 + j];
  float v_r = ws[WS_V + j], v_z = ws[WS_V + 64 + j], v_n = ws[WS_V + 128 + j];
  float bh_r = bhh[j], bh_z = bhh[64 + j], bh_n = bhh[128 + j];
  float wd = Wd[j];
  float bdv = bd[0];
  float c_r[4], c_z[4], c_n[4], h[4];
#pragma unroll
  for (int s = 0; s < 4; s++) {           // hoist t-invariant bias terms
    float rsv = ws[WS_ROWSUM + nbase + s];
    c_r[s] = rsv * u_r + v_r + bh_r;
    c_z[s] = rsv * u_z + v_z + bh_z;
    c_n[s] = rsv * u_n + v_n;
    h[s] = 0.0f;
  }

  for (int t = 0; t < T_; t++) {
    int bt = b * T_ + t;
    const float* xab = ws + WS_XA + (size_t)bt * N_ * F_;
    float xar[4];
#pragma unroll
    for (int s = 0; s < 4; s++) xar[s] = xab[(nbase + s) * F_ + (j & 31)];

    float ar[4], az[4], an[4], ag[4];
#pragma unroll
    for (int s = 0; s < 4; s++) { ar[s] = 0.f; az[s] = 0.f; an[s] = 0.f; ag[s] = 0.f; }

#pragma unroll 8
    for (int f = 0; f < 32; f++) {          // gi part: xa @ Wx
      float wxr = Xr[f * 64 + j], wxz = Xz[f * 64 + j], wxn = Xn[f * 64 + j];
#pragma unroll
      for (int s = 0; s < 4; s++) {
        float xv = lanebc(xar[s], f);
        ar[s] += xv * wxr; az[s] += xv * wxz; an[s] += xv * wxn;
      }
    }
#pragma unroll 8
    for (int k = 0; k < 64; k++) {          // gh part: h @ W_hh
      float wr_ = Wr[k * 64 + j], wz_ = Wz[k * 64 + j], wn_ = Wn[k * 64 + j];
#pragma unroll
      for (int s = 0; s < 4; s++) {
        float hv = lanebc(h[s], k);
        ar[s] += hv * wr_; az[s] += hv * wz_; ag[s] += hv * wn_;
      }
    }
#pragma unroll
    for (int s = 0; s < 4; s++) {
      float r = 1.0f / (1.0f + __expf(-(ar[s] + c_r[s])));
      float z = 1.0f / (1.0f + __expf(-(az[s] + c_z[s])));
      float nn = tanhf(an[s] + c_n[s] + r * (ag[s] + bh_n));
      h[s] = (1.0f - z) * nn + z * h[s];
    }
#pragma unroll
    for (int s = 0; s < 4; s++) {           // out = h @ W_dense + b_dense
      float o = h[s] * wd;
#pragma unroll
      for (int off = 32; off > 0; off >>= 1) o += __shfl_xor(o, off, 64);
      if (j == 0) out[(size_t)bt * N_ + nbase + s] = o + bdv;
    }
  }
}

extern "C" void kernel_launch(void* const* d_in, const int* in_sizes, int n_in,
                              void* d_out, int out_size, void* d_ws, size_t ws_size,
                              hipStream_t stream) {
  const float* x     = (const float*)d_in[0];
  const float* adj   = (const float*)d_in[1];
  const float* gamma = (const float*)d_in[2];
  const float* beta  = (const float*)d_in[3];
  const float* Wg    = (const float*)d_in[4];
  const float* bg    = (const float*)d_in[5];
  const float* Wih   = (const float*)d_in[6];
  const float* Whh   = (const float*)d_in[7];
  const float* bih   = (const float*)d_in[8];
  const float* bhh   = (const float*)d_in[9];
  const float* Wd    = (const float*)d_in[10];
  const float* bd    = (const float*)d_in[11];
  float* ws = (float*)d_ws;
  float* out = (float*)d_out;

  hipMemsetAsync(ws, 0, 64 * sizeof(float), stream);           // zero bnsum only
  k_bn_stats<<<1024, 256, 0, stream>>>(x, ws);
  k_fold<<<1, 256, 0, stream>>>(gamma, beta, Wg, bg, Wih, bih, ws);
  k_csr<<<N_, 256, 0, stream>>>(adj, ws);
  k_agg<<<BT_ * 512, 256, 0, stream>>>(x, ws);
  k_gru<<<ROWS_ / 16, 256, 0, stream>>>(Whh, bhh, Wd, bd, ws, out);
}

// Round 4
// 312.539 us; speedup vs baseline: 1.7683x; 1.1270x over previous
//
#include <hip/hip_runtime.h>
#include <hip/hip_bf16.h>

#define B_ 4
#define T_ 8
#define N_ 4096
#define F_ 32
#define C_ 32
#define H_ 64
#define BT_ (B_*T_)
#define ROWS_ (B_*N_)
#define CAP_ 128
#define EPS_ 1e-5f
#define NELEM_ (B_*T_*N_*F_)

// ---- workspace layout (float offsets) ----
#define WS_BNP   0                        // 256 blocks * 64 partials (sum[32],sumsq[32])
#define WS_WX    (256*64)                 // 32*192
#define WS_U     (WS_WX + 32*192)         // 192
#define WS_V     (WS_U + 192)             // 192
#define WS_ROWSUM (WS_V + 192)            // 4096
#define WS_DEG   (WS_ROWSUM + 4096)       // 4096 (int)
#define WS_PAIR  (WS_DEG + 4096)          // 4096*CAP_*2 floats, (idx_bits, val) pairs
#define WS_XA    (WS_PAIR + 4096*CAP_*2)  // BT_*N_*F_  (aggregated raw x)

typedef float v4f __attribute__((ext_vector_type(4)));

__device__ inline float lanebc(float v, int l) {
  return __int_as_float(__builtin_amdgcn_readlane(__float_as_int(v), l));
}
__device__ inline float sigm_f(float x) {               // ~1e-6 abs err
  return __builtin_amdgcn_rcpf(1.0f + __expf(-x));
}

// ---- K1: batchnorm stats -> per-block partials (NO atomics) ----
__global__ void __launch_bounds__(256)
k_bn_stats(const float* __restrict__ x, float* __restrict__ ws) {
  const float4* x4 = (const float4*)x;
  int tid = blockIdx.x * 256 + threadIdx.x;
  float s[4] = {0,0,0,0}, s2[4] = {0,0,0,0};
  for (int i = tid; i < NELEM_ / 4; i += 256 * 256) {   // (4i)%32 fixed per thread
    float4 v = x4[i];
    s[0] += v.x; s2[0] += v.x * v.x;
    s[1] += v.y; s2[1] += v.y * v.y;
    s[2] += v.z; s2[2] += v.z * v.z;
    s[3] += v.w; s2[3] += v.w * v.w;
  }
  __shared__ float ls[256][4], ls2[256][4];
  for (int r = 0; r < 4; r++) { ls[threadIdx.x][r] = s[r]; ls2[threadIdx.x][r] = s2[r]; }
  __syncthreads();
  int t = threadIdx.x;
  if (t < 64) {                     // channel c = 4*(q%8)+r  for q covering c
    int g = t >> 2, r = t & 3;
    float a = 0.f, b = 0.f;
    for (int w = 0; w < 32; w++) { int q = g + 8 * w; a += ls[q][r]; b += ls2[q][r]; }
    ws[WS_BNP + blockIdx.x * 64 + t] = 0.f * b + a;     // sum
    ws[WS_BNP + blockIdx.x * 64 + t] = a;
    // store sumsq in second half of the 64: use channels 32..63 slot below
    // (we pack: slot t<32 = sum[c], but need both) -- handled via t<32 path:
  }
  __syncthreads();
  if (t < 32) {
    int g = t >> 2, r = t & 3;
    float b = 0.f;
    for (int w = 0; w < 32; w++) { int q = g + 8 * w; b += ls2[q][r]; }
    ws[WS_BNP + blockIdx.x * 64 + 32 + t] = b;
  } else if (t < 64) {
    int c = t - 32;                 // redo sum for channels 0..31 properly
    int g = c >> 2, r = c & 3;
    float a = 0.f;
    for (int w = 0; w < 32; w++) { int q = g + 8 * w; a += ls[q][r]; }
    ws[WS_BNP + blockIdx.x * 64 + c] = a;
  }
}

// ---- K2: reduce partials, fold BN + W_gcn + W_ih into Wx[32][192], u, v ----
__global__ void __launch_bounds__(256)
k_fold(const float* __restrict__ gamma, const float* __restrict__ beta,
       const float* __restrict__ Wg, const float* __restrict__ bg,
       const float* __restrict__ Wih, const float* __restrict__ bih,
       float* __restrict__ ws) {
  __shared__ float bns[64];
  __shared__ float scale_s[32], shift_s[32], p_s[32];
  int t = threadIdx.x;
  if (t < 64) {
    float a = 0.f;
    for (int p = 0; p < 256; p++) a += ws[WS_BNP + p * 64 + t];
    bns[t] = a;
  }
  __syncthreads();
  if (t < 32) {
    float cnt = (float)(B_ * T_ * N_);
    float mean = bns[t] / cnt;
    float var = bns[32 + t] / cnt - mean * mean;
    float sc = gamma[t] * rsqrtf(var + EPS_);
    scale_s[t] = sc;
    shift_s[t] = beta[t] - mean * sc;
  }
  __syncthreads();
  if (t < 32) {  // p[c] = sum_f shift[f] * Wg[f][c]
    float acc = 0.f;
    for (int f = 0; f < 32; f++) acc += shift_s[f] * Wg[f * 32 + t];
    p_s[t] = acc;
  }
  __syncthreads();
  for (int e = t; e < 32 * 192; e += 256) {   // Wx[f][j] = scale[f]*sum_c Wg[f][c]*Wih[c][j]
    int f = e / 192, j = e % 192;
    float acc = 0.f;
    for (int c = 0; c < 32; c++) acc += Wg[f * 32 + c] * Wih[c * 192 + j];
    ws[WS_WX + e] = scale_s[f] * acc;
  }
  for (int j = t; j < 192; j += 256) {
    float au = 0.f, av = 0.f;
    for (int c = 0; c < 32; c++) { au += p_s[c] * Wih[c * 192 + j]; av += bg[c] * Wih[c * 192 + j]; }
    ws[WS_U + j] = au;
    ws[WS_V + j] = av + bih[j];
  }
}

// ---- K3: build fixed-capacity CSR (interleaved idx/val pairs) ----
__global__ void __launch_bounds__(256)
k_csr(const float* __restrict__ A, float* __restrict__ ws) {
  int m = blockIdx.x;
  __shared__ int cnt;
  __shared__ float rsum[256];
  if (threadIdx.x == 0) cnt = 0;
  __syncthreads();
  int* deg = (int*)&ws[WS_DEG];
  float2* pair = (float2*)&ws[WS_PAIR];
  float lsum = 0.f;
  for (int n = threadIdx.x; n < N_; n += 256) {
    float a = A[(size_t)m * N_ + n];
    if (a != 0.0f) {
      int p = atomicAdd(&cnt, 1);
      if (p < CAP_) pair[(size_t)m * CAP_ + p] = make_float2(__int_as_float(0), 0.0f), // placate sched
      pair[(size_t)m * CAP_ + p] = make_float2(__int_as_float(n), a);
      lsum += a;
    }
  }
  rsum[threadIdx.x] = lsum;
  __syncthreads();                     // cnt final here
  int c = cnt;
  for (int p = c + threadIdx.x; p < 64; p += 256)   // zero-fill so k_agg runs un-predicated
    pair[(size_t)m * CAP_ + p] = make_float2(__int_as_float(0), 0.0f);
  for (int s = 128; s > 0; s >>= 1) {
    if (threadIdx.x < s) rsum[threadIdx.x] += rsum[threadIdx.x + s];
    __syncthreads();
  }
  if (threadIdx.x == 0) { deg[m] = min(c, CAP_); ws[WS_ROWSUM + m] = rsum[0]; }
}

// ---- K4: sparse aggregation  xa[bt][m][f] = sum_k val*x[bt][idx][f] ----
__global__ void __launch_bounds__(256)
k_agg(const float* __restrict__ x, float* __restrict__ ws) {
  int bt = blockIdx.x >> 9;
  int mg = blockIdx.x & 511;
  int g = threadIdx.x >> 5, f = threadIdx.x & 31;
  int m = mg * 8 + g;
  const int* deg = (const int*)&ws[WS_DEG];
  const float2* pair = (const float2*)&ws[WS_PAIR];
  __shared__ float2 pl[8 * 64];
  for (int q = threadIdx.x; q < 512; q += 256) {
    int r = q >> 6, sl = q & 63;
    pl[q] = pair[(size_t)(mg * 8 + r) * CAP_ + sl];
  }
  __syncthreads();
  int d = deg[m];
  int dm = min(d, 64);
  int bound = max(dm, __shfl_xor(dm, 32, 64));   // wave-uniform; zero-fill makes extras safe
  const float* xb = x + (size_t)bt * N_ * F_;
  float acc = 0.f;
#pragma unroll 4
  for (int k = 0; k < bound; k++) {
    float2 p = pl[g * 64 + k];
    int n = __float_as_int(p.x);
    acc += p.y * xb[n * F_ + f];
  }
  if (d > 64) {                                  // statistically never (avg deg ~32)
    for (int k = 64; k < d; k++) {
      float2 p = pair[(size_t)m * CAP_ + k];
      acc += p.y * xb[__float_as_int(p.x) * F_ + f];
    }
  }
  ws[WS_XA + (size_t)bt * N_ * F_ + m * F_ + f] = acc;
}

// ---- K5: fused gi-projection + GRU scan + dense head ----
// 1024-thr block (16 waves, 64 rows) shares one 96 KB LDS weight image.
// wave = 64 j-lanes owns 4 rows; h[row][j] in lane j's register.
// W4[k][j]=(Wr,Wz,0,Wn), X4[f][j]=(Xr,Xz,Xn,0): acc4 += w4*scalar -> v_pk_fma_f32 x2.
__global__ void __launch_bounds__(1024, 4)
k_gru(const float* __restrict__ Whh, const float* __restrict__ bhh,
      const float* __restrict__ Wd, const float* __restrict__ bd,
      const float* __restrict__ ws, float* __restrict__ out) {
  __shared__ v4f W4[64 * 64];
  __shared__ v4f X4[32 * 64];
  int tid = threadIdx.x;
  for (int e = tid; e < 64 * 64; e += 1024) {
    int k = e >> 6, j = e & 63;
    v4f w; w.x = Whh[k * 192 + j]; w.y = Whh[k * 192 + 64 + j]; w.z = 0.f; w.w = Whh[k * 192 + 128 + j];
    W4[e] = w;
  }
  const float* wx = ws + WS_WX;
  for (int e = tid; e < 32 * 64; e += 1024) {
    int f = e >> 6, j = e & 63;
    v4f w; w.x = wx[f * 192 + j]; w.y = wx[f * 192 + 64 + j]; w.z = wx[f * 192 + 128 + j]; w.w = 0.f;
    X4[e] = w;
  }
  __syncthreads();

  int wid = tid >> 6, j = tid & 63;
  int base = blockIdx.x * 64 + wid * 4;   // this wave's 4 rows
  int b = base >> 12;                     // N_=4096
  int nbase = base & (N_ - 1);
  float u_r = ws[WS_U + j], u_z = ws[WS_U + 64 + j], u_n = ws[WS_U + 128 + j];
  float v_r = ws[WS_V + j], v_z = ws[WS_V + 64 + j], v_n = ws[WS_V + 128 + j];
  float bh_r = bhh[j], bh_z = bhh[64 + j], bh_n = bhh[128 + j];
  float wd = Wd[j];
  float bdv = bd[0];
  v4f c4[4];
  float h[4];
#pragma unroll
  for (int s = 0; s < 4; s++) {
    float rsv = ws[WS_ROWSUM + nbase + s];
    c4[s].x = rsv * u_r + v_r + bh_r;
    c4[s].y = rsv * u_z + v_z + bh_z;
    c4[s].z = rsv * u_n + v_n;
    c4[s].w = bh_n;
    h[s] = 0.0f;
  }
  // prefetch xa for t=0
  float xan[4];
  {
    const float* xab = ws + WS_XA + (size_t)(b * T_) * N_ * F_;
#pragma unroll
    for (int s = 0; s < 4; s++) xan[s] = xab[(nbase + s) * F_ + (j & 31)];
  }

  for (int t = 0; t < T_; t++) {
    float xar[4];
#pragma unroll
    for (int s = 0; s < 4; s++) xar[s] = xan[s];
    if (t < T_ - 1) {                   // software-pipeline next t's xa loads
      const float* xab = ws + WS_XA + (size_t)(b * T_ + t + 1) * N_ * F_;
#pragma unroll
      for (int s = 0; s < 4; s++) xan[s] = xab[(nbase + s) * F_ + (j & 31)];
    }
    v4f a4[4];
#pragma unroll
    for (int s = 0; s < 4; s++) a4[s] = c4[s];

#pragma unroll 8
    for (int f = 0; f < 32; f++) {      // gi: xa @ Wx  (acc .x .y .z)
      v4f w = X4[f * 64 + j];
#pragma unroll
      for (int s = 0; s < 4; s++) a4[s] += w * lanebc(xar[s], f);
    }
#pragma unroll 8
    for (int k = 0; k < 64; k++) {      // gh: h @ W_hh (acc .x .y .w)
      v4f w = W4[k * 64 + j];
#pragma unroll
      for (int s = 0; s < 4; s++) a4[s] += w * lanebc(h[s], k);
    }
#pragma unroll
    for (int s = 0; s < 4; s++) {
      v4f a = a4[s];
      float r = sigm_f(a.x);
      float z = sigm_f(a.y);
      float nn = 2.0f * sigm_f(2.0f * (a.z + r * a.w)) - 1.0f;   // tanh
      h[s] = z * (h[s] - nn) + nn;
    }
    int bt = b * T_ + t;
#pragma unroll
    for (int s = 0; s < 4; s++) {       // out = h @ W_dense + b_dense
      float o = h[s] * wd;
#pragma unroll
      for (int off = 32; off > 0; off >>= 1) o += __shfl_xor(o, off, 64);
      if (j == 0) out[(size_t)bt * N_ + nbase + s] = o + bdv;
    }
  }
}

extern "C" void kernel_launch(void* const* d_in, const int* in_sizes, int n_in,
                              void* d_out, int out_size, void* d_ws, size_t ws_size,
                              hipStream_t stream) {
  const float* x     = (const float*)d_in[0];
  const float* adj   = (const float*)d_in[1];
  const float* gamma = (const float*)d_in[2];
  const float* beta  = (const float*)d_in[3];
  const float* Wg    = (const float*)d_in[4];
  const float* bg    = (const float*)d_in[5];
  const float* Wih   = (const float*)d_in[6];
  const float* Whh   = (const float*)d_in[7];
  const float* bih   = (const float*)d_in[8];
  const float* bhh   = (const float*)d_in[9];
  const float* Wd    = (const float*)d_in[10];
  const float* bd    = (const float*)d_in[11];
  float* ws = (float*)d_ws;
  float* out = (float*)d_out;

  k_bn_stats<<<256, 256, 0, stream>>>(x, ws);
  k_fold<<<1, 256, 0, stream>>>(gamma, beta, Wg, bg, Wih, bih, ws);
  k_csr<<<N_, 256, 0, stream>>>(adj, ws);
  k_agg<<<BT_ * 512, 256, 0, stream>>>(x, ws);
  k_gru<<<ROWS_ / 64, 1024, 0, stream>>>(Whh, bhh, Wd, bd, ws, out);
}

// Round 5
// 285.507 us; speedup vs baseline: 1.9358x; 1.0947x over previous
//
#include <hip/hip_runtime.h>
#include <hip/hip_bf16.h>

#define B_ 4
#define T_ 8
#define N_ 4096
#define F_ 32
#define C_ 32
#define H_ 64
#define BT_ (B_*T_)
#define ROWS_ (B_*N_)
#define CAP_ 128
#define EPS_ 1e-5f
#define NELEM_ (B_*T_*N_*F_)

// ---- workspace layout (float offsets) ----
#define WS_BNP   0                        // 256 virt-blocks * 64 partials (sum[32],sumsq[32])
#define WS_ROWSUM (256*64)                // 4096
#define WS_DEG   (WS_ROWSUM + 4096)       // 4096 (int)
#define WS_PAIR  (WS_DEG + 4096)          // 4096*CAP_*2 floats, (idx_bits, val) pairs
#define WS_XA    (WS_PAIR + 4096*CAP_*2)  // BT_*N_*F_  (aggregated raw x)

typedef float v4f __attribute__((ext_vector_type(4)));

__device__ inline float lanebc(float v, int l) {
  return __int_as_float(__builtin_amdgcn_readlane(__float_as_int(v), l));
}
__device__ inline float sigm_f(float x) {
  return __builtin_amdgcn_rcpf(1.0f + __expf(-x));
}

// ---- K1: merged CSR build (blocks 0..4095) + BN partial stats (4096..4351) ----
__global__ void __launch_bounds__(256)
k_pre(const float* __restrict__ x, const float* __restrict__ A, float* __restrict__ ws) {
  if (blockIdx.x < 4096) {
    // ---- CSR row m ----
    int m = blockIdx.x;
    __shared__ int cnt;
    __shared__ float rsum[256];
    if (threadIdx.x == 0) cnt = 0;
    __syncthreads();
    int* deg = (int*)&ws[WS_DEG];
    float2* pair = (float2*)&ws[WS_PAIR];
    const float4* A4 = (const float4*)(A + (size_t)m * N_);
    float lsum = 0.f;
    for (int q = threadIdx.x; q < N_ / 4; q += 256) {
      float4 a4 = A4[q];
      float av[4] = {a4.x, a4.y, a4.z, a4.w};
#pragma unroll
      for (int r = 0; r < 4; r++) {
        float a = av[r];
        if (a != 0.0f) {
          int p = atomicAdd(&cnt, 1);
          if (p < CAP_) pair[(size_t)m * CAP_ + p] = make_float2(__int_as_float(4 * q + r), a);
          lsum += a;
        }
      }
    }
    rsum[threadIdx.x] = lsum;
    __syncthreads();                     // cnt final here
    int c = cnt;
    for (int p = c + threadIdx.x; p < 64; p += 256)   // zero-fill so k_agg runs un-predicated
      pair[(size_t)m * CAP_ + p] = make_float2(__int_as_float(0), 0.0f);
    for (int s = 128; s > 0; s >>= 1) {
      if (threadIdx.x < s) rsum[threadIdx.x] += rsum[threadIdx.x + s];
      __syncthreads();
    }
    if (threadIdx.x == 0) { deg[m] = min(c, CAP_); ws[WS_ROWSUM + m] = rsum[0]; }
  } else {
    // ---- BN partials, virtual block bnb in [0,256) ----
    int bnb = blockIdx.x - 4096;
    const float4* x4 = (const float4*)x;
    int tid = bnb * 256 + threadIdx.x;
    float s[4] = {0,0,0,0}, s2[4] = {0,0,0,0};
    for (int i = tid; i < NELEM_ / 4; i += 256 * 256) {  // stride ≡ 0 mod 8 -> channels fixed
      float4 v = x4[i];
      s[0] += v.x; s2[0] += v.x * v.x;
      s[1] += v.y; s2[1] += v.y * v.y;
      s[2] += v.z; s2[2] += v.z * v.z;
      s[3] += v.w; s2[3] += v.w * v.w;
    }
    __shared__ float ls[256][4], ls2[256][4];
#pragma unroll
    for (int r = 0; r < 4; r++) { ls[threadIdx.x][r] = s[r]; ls2[threadIdx.x][r] = s2[r]; }
    __syncthreads();
    int t = threadIdx.x;
    if (t < 32) {                 // channel c = 4*(q&7)+r
      int g = t >> 2, r = t & 3;
      float a = 0.f;
      for (int q = g; q < 256; q += 8) a += ls[q][r];
      ws[WS_BNP + bnb * 64 + t] = a;
    } else if (t < 64) {
      int cch = t - 32;
      int g = cch >> 2, r = cch & 3;
      float b2 = 0.f;
      for (int q = g; q < 256; q += 8) b2 += ls2[q][r];
      ws[WS_BNP + bnb * 64 + t] = b2;
    }
  }
}

// ---- K2: sparse aggregation, 2 timeslices per block ----
// xa[bt][m][f] = sum_k val*x[bt][idx][f];  8 rows/block, pairs staged in LDS.
__global__ void __launch_bounds__(256)
k_agg(const float* __restrict__ x, float* __restrict__ ws) {
  int chunk = blockIdx.x >> 9;            // 16 chunks of 2 bt
  int mg = blockIdx.x & 511;
  int g = threadIdx.x >> 5, f = threadIdx.x & 31;
  int m = mg * 8 + g;
  const int* deg = (const int*)&ws[WS_DEG];
  const float2* pair = (const float2*)&ws[WS_PAIR];
  __shared__ float2 pl[8 * 64];
  for (int q = threadIdx.x; q < 512; q += 256) {
    int r = q >> 6, sl = q & 63;
    pl[q] = pair[(size_t)(mg * 8 + r) * CAP_ + sl];
  }
  __syncthreads();
  int d = deg[m];
  int dm = min(d, 64);
  int bound = max(dm, __shfl_xor(dm, 32, 64));   // wave-uniform; zero-fill makes extras safe
  int bt0 = chunk * 2;
  const float* xb0 = x + (size_t)bt0 * N_ * F_;
  const float* xb1 = xb0 + N_ * F_;
  float acc0 = 0.f, acc1 = 0.f;
#pragma unroll 8
  for (int k = 0; k < bound; k++) {
    float2 p = pl[g * 64 + k];
    int off = __float_as_int(p.x) * F_ + f;
    acc0 += p.y * xb0[off];
    acc1 += p.y * xb1[off];
  }
  if (d > 64) {                                  // statistically never (avg deg ~32)
    for (int k = 64; k < d; k++) {
      float2 p = pair[(size_t)m * CAP_ + k];
      int off = __float_as_int(p.x) * F_ + f;
      acc0 += p.y * xb0[off];
      acc1 += p.y * xb1[off];
    }
  }
  ws[WS_XA + (size_t)bt0 * N_ * F_ + m * F_ + f] = acc0;
  ws[WS_XA + (size_t)(bt0 + 1) * N_ * F_ + m * F_ + f] = acc1;
}

// ---- K3: inline fold + fused gi-projection + GRU scan + dense head ----
// 512-thr block = 8 waves; wave owns 8 rows (64 rows/block, grid=256=1/CU).
// W4[k][j]=(Wr,Wz,0,Wn), X4[f][j]=(Xr,Xz,Xn,0): a4 += w4*scalar -> 2x v_pk_fma_f32.
__global__ void __launch_bounds__(512, 2)
k_gru(const float* __restrict__ Whh, const float* __restrict__ bhh,
      const float* __restrict__ Wd, const float* __restrict__ bd,
      const float* __restrict__ gamma, const float* __restrict__ beta,
      const float* __restrict__ Wg, const float* __restrict__ bg,
      const float* __restrict__ Wih, const float* __restrict__ bih,
      const float* __restrict__ ws, float* __restrict__ out) {
  __shared__ v4f W4[64 * 64];           // 64 KB
  __shared__ v4f X4[32 * 64];           // 32 KB
  __shared__ float Us[192], Vs[192];
  __shared__ float bns[64], scale_s[32], shift_s[32], p_s[32];
  int tid = threadIdx.x;
  for (int e = tid; e < 64 * 64; e += 512) {
    int k = e >> 6, j = e & 63;
    v4f w; w.x = Whh[k * 192 + j]; w.y = Whh[k * 192 + 64 + j]; w.z = 0.f; w.w = Whh[k * 192 + 128 + j];
    W4[e] = w;
  }
  if (tid < 64) {                       // reduce BN partials
    float a = 0.f;
    for (int p = 0; p < 256; p++) a += ws[WS_BNP + p * 64 + tid];
    bns[tid] = a;
  }
  __syncthreads();
  if (tid < 32) {
    float cnt = (float)(B_ * T_ * N_);
    float mean = bns[tid] / cnt;
    float var = bns[32 + tid] / cnt - mean * mean;
    float sc = gamma[tid] * rsqrtf(var + EPS_);
    scale_s[tid] = sc;
    shift_s[tid] = beta[tid] - mean * sc;
  }
  __syncthreads();
  if (tid < 32) {                       // p[c] = sum_f shift[f]*Wg[f][c]
    float acc = 0.f;
    for (int f = 0; f < 32; f++) acc += shift_s[f] * Wg[f * 32 + tid];
    p_s[tid] = acc;
  }
  __syncthreads();
  if (tid < 192) {                      // u, v
    float au = 0.f, av = 0.f;
    for (int c = 0; c < 32; c++) { au += p_s[c] * Wih[c * 192 + tid]; av += bg[c] * Wih[c * 192 + tid]; }
    Us[tid] = au; Vs[tid] = av + bih[tid];
  }
  for (int e = tid; e < 32 * 64; e += 512) {  // Wx = diag(scale)*Wg*Wih, packed
    int f = e >> 6, j = e & 63;
    float ar = 0.f, az = 0.f, an = 0.f;
    for (int c = 0; c < 32; c++) {
      float wg = Wg[f * 32 + c];
      ar += wg * Wih[c * 192 + j];
      az += wg * Wih[c * 192 + 64 + j];
      an += wg * Wih[c * 192 + 128 + j];
    }
    float sc = scale_s[f];
    v4f w; w.x = sc * ar; w.y = sc * az; w.z = sc * an; w.w = 0.f;
    X4[e] = w;
  }
  __syncthreads();

  int wid = tid >> 6, j = tid & 63;
  int base = blockIdx.x * 64 + wid * 8;   // this wave's 8 rows
  int b = base >> 12;                     // N_=4096
  int nbase = base & (N_ - 1);
  v4f u4, vb4;
  u4.x = Us[j]; u4.y = Us[64 + j]; u4.z = Us[128 + j]; u4.w = 0.f;
  vb4.x = Vs[j] + bhh[j]; vb4.y = Vs[64 + j] + bhh[64 + j]; vb4.z = Vs[128 + j]; vb4.w = bhh[128 + j];
  float wd = Wd[j];
  float bdv = bd[0];
  float rsv[8], h[8];
#pragma unroll
  for (int s = 0; s < 8; s++) { rsv[s] = ws[WS_ROWSUM + nbase + s]; h[s] = 0.0f; }

  float xan[8];                           // software-pipelined xa loads
  {
    const float* xab = ws + WS_XA + (size_t)(b * T_) * N_ * F_;
#pragma unroll
    for (int s = 0; s < 8; s++) xan[s] = xab[(nbase + s) * F_ + (j & 31)];
  }

  for (int t = 0; t < T_; t++) {
    float xar[8];
#pragma unroll
    for (int s = 0; s < 8; s++) xar[s] = xan[s];
    if (t < T_ - 1) {
      const float* xab = ws + WS_XA + (size_t)(b * T_ + t + 1) * N_ * F_;
#pragma unroll
      for (int s = 0; s < 8; s++) xan[s] = xab[(nbase + s) * F_ + (j & 31)];
    }
    v4f a4[8];
#pragma unroll
    for (int s = 0; s < 8; s++) a4[s] = vb4 + u4 * rsv[s];

#pragma unroll 8
    for (int f = 0; f < 32; f++) {        // gi: xa @ Wx  (acc .x .y .z)
      v4f w = X4[f * 64 + j];
#pragma unroll
      for (int s = 0; s < 8; s++) a4[s] += w * lanebc(xar[s], f);
    }
#pragma unroll 8
    for (int k = 0; k < 64; k++) {        // gh: h @ W_hh (acc .x .y .w)
      v4f w = W4[k * 64 + j];
#pragma unroll
      for (int s = 0; s < 8; s++) a4[s] += w * lanebc(h[s], k);
    }
#pragma unroll
    for (int s = 0; s < 8; s++) {
      v4f a = a4[s];
      float r = sigm_f(a.x);
      float z = sigm_f(a.y);
      float nn = 2.0f * sigm_f(2.0f * (a.z + r * a.w)) - 1.0f;   // tanh
      h[s] = z * (h[s] - nn) + nn;
    }
    int bt = b * T_ + t;
#pragma unroll
    for (int s = 0; s < 8; s++) {         // out = h @ W_dense + b_dense
      float o = h[s] * wd;
#pragma unroll
      for (int off = 32; off > 0; off >>= 1) o += __shfl_xor(o, off, 64);
      if (j == 0) out[(size_t)bt * N_ + nbase + s] = o + bdv;
    }
  }
}

extern "C" void kernel_launch(void* const* d_in, const int* in_sizes, int n_in,
                              void* d_out, int out_size, void* d_ws, size_t ws_size,
                              hipStream_t stream) {
  const float* x     = (const float*)d_in[0];
  const float* adj   = (const float*)d_in[1];
  const float* gamma = (const float*)d_in[2];
  const float* beta  = (const float*)d_in[3];
  const float* Wg    = (const float*)d_in[4];
  const float* bg    = (const float*)d_in[5];
  const float* Wih   = (const float*)d_in[6];
  const float* Whh   = (const float*)d_in[7];
  const float* bih   = (const float*)d_in[8];
  const float* bhh   = (const float*)d_in[9];
  const float* Wd    = (const float*)d_in[10];
  const float* bd    = (const float*)d_in[11];
  float* ws = (float*)d_ws;
  float* out = (float*)d_out;

  k_pre<<<4096 + 256, 256, 0, stream>>>(x, adj, ws);
  k_agg<<<(BT_ / 2) * 512, 256, 0, stream>>>(x, ws);
  k_gru<<<ROWS_ / 64, 512, 0, stream>>>(Whh, bhh, Wd, bd, gamma, beta, Wg, bg, Wih, bih, ws, out);
}

// Round 6
// 222.635 us; speedup vs baseline: 2.4824x; 1.2824x over previous
//
#include <hip/hip_runtime.h>
#include <hip/hip_bf16.h>
#include <stdint.h>

#define B_ 4
#define T_ 8
#define N_ 4096
#define F_ 32
#define BT_ (B_*T_)
#define ROWS_ (B_*N_)
#define CAP_ 128
#define EPS_ 1e-5f
#define NELEM_ (B_*T_*N_*F_)

// ---- workspace layout (float offsets) ----
#define WS_BNP    0                       // 256 * 64 partials
#define WS_ROWSUM 16384                   // 4096
#define WS_DEG    (WS_ROWSUM + 4096)      // 4096 (int)
#define WS_FRG    (WS_DEG + 4096)         // 52 frags * 64 lanes * 4 dwords = 13312
#define WS_PAIR   (WS_FRG + 52*256)       // 4096*CAP_*2
#define WS_XA     (WS_PAIR + 4096*CAP_*2) // BT_*N_*F_

typedef float v4f __attribute__((ext_vector_type(4)));
typedef _Float16 half8 __attribute__((ext_vector_type(8)));
union HU { uint32_t u[4]; half8 v; };

__device__ inline float sigm_f(float x) {
  return __builtin_amdgcn_rcpf(1.0f + __expf(-x));
}
__device__ inline uint32_t f16pair(float a, float b) {
  union { _Float16 h; unsigned short s; } x, y;
  x.h = (_Float16)a; y.h = (_Float16)b;
  return (uint32_t)x.s | ((uint32_t)y.s << 16);
}
// split a0,a1 into fp16 hi/lo packed pairs
__device__ inline void sp2(float a0, float a1, uint32_t& hi, uint32_t& lo) {
  _Float16 h0 = (_Float16)a0, h1 = (_Float16)a1;
  float r0 = a0 - (float)h0, r1 = a1 - (float)h1;
  union { _Float16 h; unsigned short s; } u0, u1, v0, v1;
  u0.h = h0; u1.h = h1; v0.h = (_Float16)r0; v1.h = (_Float16)r1;
  hi = (uint32_t)u0.s | ((uint32_t)u1.s << 16);
  lo = (uint32_t)v0.s | ((uint32_t)v1.s << 16);
}

// ---- K1: merged CSR build (blocks 0..4095) + BN partial stats (4096..4351) ----
__global__ void __launch_bounds__(256)
k_pre(const float* __restrict__ x, const float* __restrict__ A, float* __restrict__ ws) {
  if (blockIdx.x < 4096) {
    int m = blockIdx.x;
    __shared__ int cnt;
    __shared__ float rsum[256];
    if (threadIdx.x == 0) cnt = 0;
    __syncthreads();
    int* deg = (int*)&ws[WS_DEG];
    float2* pair = (float2*)&ws[WS_PAIR];
    const float4* A4 = (const float4*)(A + (size_t)m * N_);
    float lsum = 0.f;
    for (int q = threadIdx.x; q < N_ / 4; q += 256) {
      float4 a4 = A4[q];
      float av[4] = {a4.x, a4.y, a4.z, a4.w};
#pragma unroll
      for (int r = 0; r < 4; r++) {
        float a = av[r];
        if (a != 0.0f) {
          int p = atomicAdd(&cnt, 1);
          if (p < CAP_) pair[(size_t)m * CAP_ + p] = make_float2(__int_as_float(4 * q + r), a);
          lsum += a;
        }
      }
    }
    rsum[threadIdx.x] = lsum;
    __syncthreads();
    int c = cnt;
    for (int p = c + threadIdx.x; p < 64; p += 256)
      pair[(size_t)m * CAP_ + p] = make_float2(__int_as_float(0), 0.0f);
    for (int s = 128; s > 0; s >>= 1) {
      if (threadIdx.x < s) rsum[threadIdx.x] += rsum[threadIdx.x + s];
      __syncthreads();
    }
    if (threadIdx.x == 0) { deg[m] = min(c, CAP_); ws[WS_ROWSUM + m] = rsum[0]; }
  } else {
    int bnb = blockIdx.x - 4096;
    const float4* x4 = (const float4*)x;
    int tid = bnb * 256 + threadIdx.x;
    float s[4] = {0,0,0,0}, s2[4] = {0,0,0,0};
    for (int i = tid; i < NELEM_ / 4; i += 256 * 256) {
      float4 v = x4[i];
      s[0] += v.x; s2[0] += v.x * v.x;
      s[1] += v.y; s2[1] += v.y * v.y;
      s[2] += v.z; s2[2] += v.z * v.z;
      s[3] += v.w; s2[3] += v.w * v.w;
    }
    __shared__ float ls[256][4], ls2[256][4];
#pragma unroll
    for (int r = 0; r < 4; r++) { ls[threadIdx.x][r] = s[r]; ls2[threadIdx.x][r] = s2[r]; }
    __syncthreads();
    int t = threadIdx.x;
    if (t < 32) {
      int g = t >> 2, r = t & 3;
      float a = 0.f;
      for (int q = g; q < 256; q += 8) a += ls[q][r];
      ws[WS_BNP + bnb * 64 + t] = a;
    } else if (t < 64) {
      int cch = t - 32;
      int g = cch >> 2, r = cch & 3;
      float b2 = 0.f;
      for (int q = g; q < 256; q += 8) b2 += ls2[q][r];
      ws[WS_BNP + bnb * 64 + t] = b2;
    }
  }
}

// ---- K2: sparse aggregation (blocks 0..8191) + weight-fragment fold (block 8192) ----
__global__ void __launch_bounds__(256)
k_agg(const float* __restrict__ x,
      const float* __restrict__ gamma, const float* __restrict__ beta,
      const float* __restrict__ Wg, const float* __restrict__ bg,
      const float* __restrict__ Wih, const float* __restrict__ bih,
      const float* __restrict__ Whh, const float* __restrict__ bhh,
      float* __restrict__ ws) {
  __shared__ float sh[6688];
  int tid = threadIdx.x;
  if (blockIdx.x >= 8192) {
    // ---- fold: BN stats + compose W into fp16 A-fragments ----
    float* Wx_s = sh;              // [32][192]
    float* Us_s = sh + 6144;       // [192]
    float* Vs_s = sh + 6336;       // [192] (bg-fold + bih; NO bhh)
    float* bns  = sh + 6528;       // [64]
    float* scale_s = sh + 6592;    // [32]
    float* shift_s = sh + 6624;    // [32]
    float* p_s     = sh + 6656;    // [32]
    if (tid < 64) {
      float a = 0.f;
      for (int p = 0; p < 256; p++) a += ws[WS_BNP + p * 64 + tid];
      bns[tid] = a;
    }
    __syncthreads();
    if (tid < 32) {
      float cntf = (float)(B_ * T_ * N_);
      float mean = bns[tid] / cntf;
      float var = bns[32 + tid] / cntf - mean * mean;
      float sc = gamma[tid] * rsqrtf(var + EPS_);
      scale_s[tid] = sc;
      shift_s[tid] = beta[tid] - mean * sc;
    }
    __syncthreads();
    if (tid < 32) {
      float acc = 0.f;
      for (int f = 0; f < 32; f++) acc += shift_s[f] * Wg[f * 32 + tid];
      p_s[tid] = acc;
    }
    __syncthreads();
    for (int e = tid; e < 32 * 192; e += 256) {
      int f = e / 192, j = e % 192;
      float acc = 0.f;
      for (int c = 0; c < 32; c++) acc += Wg[f * 32 + c] * Wih[c * 192 + j];
      Wx_s[e] = scale_s[f] * acc;
    }
    if (tid < 192) {
      float au = 0.f, av = 0.f;
      for (int c = 0; c < 32; c++) { au += p_s[c] * Wih[c * 192 + tid]; av += bg[c] * Wih[c * 192 + tid]; }
      Us_s[tid] = au; Vs_s[tid] = av + bih[tid];
    }
    __syncthreads();
    // build 52 fragments: A'[jout = mt*16 + (lane&15)][k = kt*32 + quad*8 + e]
    int w = tid >> 6, L = tid & 63, q = L >> 4, c = L & 15;
    uint32_t* wsu = (uint32_t*)ws;
    for (int fi = w; fi < 52; fi += 4) {
      int mt, kt;
      if (fi < 32)      { mt = fi >> 2;            kt = fi & 3; }
      else if (fi < 40) { mt = 8 + ((fi - 32) >> 1); kt = (fi & 1) ? 3 : 0; }
      else              { int r = fi - 40; mt = 12 + r / 3; kt = 1 + r % 3; }
      int cls = mt >> 2;
      int col = (cls < 2) ? mt * 16 + c : 128 + (mt & 3) * 16 + c;
#pragma unroll
      for (int d = 0; d < 4; d++) {
        float a01[2];
#pragma unroll
        for (int h2 = 0; h2 < 2; h2++) {
          int k = kt * 32 + q * 8 + 2 * d + h2;
          float v;
          if (k < 32)       v = (cls == 3) ? 0.f : Wx_s[k * 192 + col];
          else if (k < 96)  v = (cls == 2) ? 0.f : Whh[(k - 32) * 192 + col];
          else if (k == 96) v = (cls == 3) ? 0.f : Us_s[col];
          else if (k == 97) v = (cls < 2) ? (Vs_s[col] + bhh[col]) : (cls == 2 ? Vs_s[col] : bhh[col]);
          else              v = 0.f;
          a01[h2] = v;
        }
        wsu[WS_FRG + fi * 256 + L * 4 + d] = f16pair(a01[0], a01[1]);
      }
    }
    return;
  }
  // ---- aggregation, 2 timeslices per block ----
  float2* pl = (float2*)sh;            // [8*64]
  int chunk = blockIdx.x >> 9;
  int mg = blockIdx.x & 511;
  int g = tid >> 5, f = tid & 31;
  int m = mg * 8 + g;
  const int* deg = (const int*)&ws[WS_DEG];
  const float2* pair = (const float2*)&ws[WS_PAIR];
  for (int qq = tid; qq < 512; qq += 256) {
    int r = qq >> 6, sl = qq & 63;
    pl[qq] = pair[(size_t)(mg * 8 + r) * CAP_ + sl];
  }
  __syncthreads();
  int d = deg[m];
  int dm = min(d, 64);
  int bound = max(dm, __shfl_xor(dm, 32, 64));
  int bt0 = chunk * 2;
  const float* xb0 = x + (size_t)bt0 * N_ * F_;
  const float* xb1 = xb0 + N_ * F_;
  float acc0 = 0.f, acc1 = 0.f;
#pragma unroll 8
  for (int k = 0; k < bound; k++) {
    float2 p = pl[g * 64 + k];
    int off = __float_as_int(p.x) * F_ + f;
    acc0 += p.y * xb0[off];
    acc1 += p.y * xb1[off];
  }
  if (d > 64) {
    for (int k = 64; k < d; k++) {
      float2 p = pair[(size_t)m * CAP_ + k];
      int off = __float_as_int(p.x) * F_ + f;
      acc0 += p.y * xb0[off];
      acc1 += p.y * xb1[off];
    }
  }
  ws[WS_XA + (size_t)bt0 * N_ * F_ + m * F_ + f] = acc0;
  ws[WS_XA + (size_t)(bt0 + 1) * N_ * F_ + m * F_ + f] = acc1;
}

// ---- K3: MFMA GRU. block = 256 thr = 4 waves; wave owns 16 rows.
// D'[jout][row] = sum_k W'[k][jout] * feat[k][row], jout in 256 cols:
//   [0,64) r | [64,128) z | [128,192) gi_n (xa+bias K only) | [192,256) gh_n (h+bias K only)
// K-tiles: 0=xa(32) 1=h[0:32) 2=h[32:64) 3=bias(rsv,1). fp16, B split hi/lo (2-pass).
#define LDA(fi) (*(const half8*)(frg + (fi)*256 + L*4))
#define DO1(mt, fi, BH, BL) { half8 af = LDA(fi); \
  acc[mt] = __builtin_amdgcn_mfma_f32_16x16x32_f16(af, BH, acc[mt], 0, 0, 0); \
  acc[mt] = __builtin_amdgcn_mfma_f32_16x16x32_f16(af, BL, acc[mt], 0, 0, 0); }

__global__ void __launch_bounds__(256, 1)
k_gru(const float* __restrict__ Wd, const float* __restrict__ bd,
      const float* __restrict__ ws, float* __restrict__ out) {
  __shared__ uint32_t frg[52 * 256];     // 53 KB weight fragments
  __shared__ uint32_t hx[4 * 1344];      // per-wave h-exchange, stride 21
  {
    const uint4* gf = (const uint4*)(ws + WS_FRG);
    uint4* sf = (uint4*)frg;
    for (int i = threadIdx.x; i < 52 * 64; i += 256) sf[i] = gf[i];
  }
  __syncthreads();
  int wid = threadIdx.x >> 6, L = threadIdx.x & 63;
  int q = L >> 4, c = L & 15;
  uint32_t* hxw = hx + wid * 1344;
  int row0 = blockIdx.x * 64 + wid * 16;
  int b = row0 >> 12;
  int nb = row0 & (N_ - 1);
  float wdv[4][4];
#pragma unroll
  for (int g = 0; g < 4; g++)
#pragma unroll
    for (int r = 0; r < 4; r++) wdv[g][r] = Wd[16 * g + 4 * q + r];
  float bdv = bd[0];
  // bias B-frag (t-invariant): k-local 0 = rowsum[row], k-local 1 = 1.0, quad 0 only
  HU b3h, b3l;
#pragma unroll
  for (int d = 0; d < 4; d++) { b3h.u[d] = 0; b3l.u[d] = 0; }
  {
    float rsv = ws[WS_ROWSUM + nb + c];
    uint32_t rhi, rlo;
    sp2(rsv, 1.0f, rhi, rlo);
    // lo of 1.0 is 0 automatically (exact)
    if (q == 0) { b3h.u[0] = rhi; b3l.u[0] = rlo & 0xFFFFu; }
  }
  float h[4][4];
#pragma unroll
  for (int g = 0; g < 4; g++)
#pragma unroll
    for (int r = 0; r < 4; r++) h[g][r] = 0.f;

  const float* xab = ws + WS_XA;
  size_t xo0 = ((size_t)(b * T_) * N_ + nb + c) * F_ + q * 8;
  float4 xaA = *(const float4*)(xab + xo0);
  float4 xaB = *(const float4*)(xab + xo0 + 4);

  for (int t = 0; t < T_; t++) {
    float4 nxA, nxB;
    if (t < T_ - 1) {
      size_t xo = ((size_t)(b * T_ + t + 1) * N_ + nb + c) * F_ + q * 8;
      nxA = *(const float4*)(xab + xo);
      nxB = *(const float4*)(xab + xo + 4);
    }
    // ---- h split/pack/exchange (intra-wave via LDS, no barrier) ----
#pragma unroll
    for (int g = 0; g < 4; g++)
#pragma unroll
      for (int rp = 0; rp < 2; rp++) {
        uint32_t phi, plo;
        sp2(h[g][2 * rp], h[g][2 * rp + 1], phi, plo);
        int pidx = 8 * g + 2 * q + rp;
        hxw[(pidx * 2 + 0) * 21 + c] = phi;
        hxw[(pidx * 2 + 1) * 21 + c] = plo;
      }
    HU b1h, b1l, b2h, b2l;
#pragma unroll
    for (int d = 0; d < 4; d++) {
      b1h.u[d] = hxw[((4 * q + d) * 2 + 0) * 21 + c];
      b1l.u[d] = hxw[((4 * q + d) * 2 + 1) * 21 + c];
      b2h.u[d] = hxw[((16 + 4 * q + d) * 2 + 0) * 21 + c];
      b2l.u[d] = hxw[((16 + 4 * q + d) * 2 + 1) * 21 + c];
    }
    v4f acc[16];
#pragma unroll
    for (int i = 0; i < 16; i++) acc[i] = (v4f){0.f, 0.f, 0.f, 0.f};
    // kt=1 (h[0:32))
    DO1(0,1,b1h.v,b1l.v)  DO1(1,5,b1h.v,b1l.v)  DO1(2,9,b1h.v,b1l.v)  DO1(3,13,b1h.v,b1l.v)
    DO1(4,17,b1h.v,b1l.v) DO1(5,21,b1h.v,b1l.v) DO1(6,25,b1h.v,b1l.v) DO1(7,29,b1h.v,b1l.v)
    DO1(12,40,b1h.v,b1l.v) DO1(13,43,b1h.v,b1l.v) DO1(14,46,b1h.v,b1l.v) DO1(15,49,b1h.v,b1l.v)
    // kt=2 (h[32:64))
    DO1(0,2,b2h.v,b2l.v)  DO1(1,6,b2h.v,b2l.v)  DO1(2,10,b2h.v,b2l.v) DO1(3,14,b2h.v,b2l.v)
    DO1(4,18,b2h.v,b2l.v) DO1(5,22,b2h.v,b2l.v) DO1(6,26,b2h.v,b2l.v) DO1(7,30,b2h.v,b2l.v)
    DO1(12,41,b2h.v,b2l.v) DO1(13,44,b2h.v,b2l.v) DO1(14,47,b2h.v,b2l.v) DO1(15,50,b2h.v,b2l.v)
    // kt=3 (bias)
    DO1(0,3,b3h.v,b3l.v)  DO1(1,7,b3h.v,b3l.v)  DO1(2,11,b3h.v,b3l.v) DO1(3,15,b3h.v,b3l.v)
    DO1(4,19,b3h.v,b3l.v) DO1(5,23,b3h.v,b3l.v) DO1(6,27,b3h.v,b3l.v) DO1(7,31,b3h.v,b3l.v)
    DO1(8,33,b3h.v,b3l.v) DO1(9,35,b3h.v,b3l.v) DO1(10,37,b3h.v,b3l.v) DO1(11,39,b3h.v,b3l.v)
    DO1(12,42,b3h.v,b3l.v) DO1(13,45,b3h.v,b3l.v) DO1(14,48,b3h.v,b3l.v) DO1(15,51,b3h.v,b3l.v)
    // kt=0 (xa)
    HU b0h, b0l;
    sp2(xaA.x, xaA.y, b0h.u[0], b0l.u[0]);
    sp2(xaA.z, xaA.w, b0h.u[1], b0l.u[1]);
    sp2(xaB.x, xaB.y, b0h.u[2], b0l.u[2]);
    sp2(xaB.z, xaB.w, b0h.u[3], b0l.u[3]);
    DO1(0,0,b0h.v,b0l.v)  DO1(1,4,b0h.v,b0l.v)  DO1(2,8,b0h.v,b0l.v)  DO1(3,12,b0h.v,b0l.v)
    DO1(4,16,b0h.v,b0l.v) DO1(5,20,b0h.v,b0l.v) DO1(6,24,b0h.v,b0l.v) DO1(7,28,b0h.v,b0l.v)
    DO1(8,32,b0h.v,b0l.v) DO1(9,34,b0h.v,b0l.v) DO1(10,36,b0h.v,b0l.v) DO1(11,38,b0h.v,b0l.v)
    // ---- gates ----
    float o = 0.f;
#pragma unroll
    for (int g = 0; g < 4; g++)
#pragma unroll
      for (int r = 0; r < 4; r++) {
        float rr = sigm_f(acc[g][r]);
        float z  = sigm_f(acc[4 + g][r]);
        float nn = 2.0f * sigm_f(2.0f * (acc[8 + g][r] + rr * acc[12 + g][r])) - 1.0f;
        float hn = z * (h[g][r] - nn) + nn;
        h[g][r] = hn;
        o += wdv[g][r] * hn;
      }
    o += __shfl_xor(o, 16, 64);
    o += __shfl_xor(o, 32, 64);
    if (L < 16) out[(size_t)(b * T_ + t) * N_ + nb + L] = o + bdv;
    xaA = nxA; xaB = nxB;
  }
}

extern "C" void kernel_launch(void* const* d_in, const int* in_sizes, int n_in,
                              void* d_out, int out_size, void* d_ws, size_t ws_size,
                              hipStream_t stream) {
  const float* x     = (const float*)d_in[0];
  const float* adj   = (const float*)d_in[1];
  const float* gamma = (const float*)d_in[2];
  const float* beta  = (const float*)d_in[3];
  const float* Wg    = (const float*)d_in[4];
  const float* bg    = (const float*)d_in[5];
  const float* Wih   = (const float*)d_in[6];
  const float* Whh   = (const float*)d_in[7];
  const float* bih   = (const float*)d_in[8];
  const float* bhh   = (const float*)d_in[9];
  const float* Wd    = (const float*)d_in[10];
  const float* bd    = (const float*)d_in[11];
  float* ws = (float*)d_ws;
  float* out = (float*)d_out;

  k_pre<<<4096 + 256, 256, 0, stream>>>(x, adj, ws);
  k_agg<<<8192 + 1, 256, 0, stream>>>(x, gamma, beta, Wg, bg, Wih, bih, Whh, bhh, ws);
  k_gru<<<256, 256, 0, stream>>>(Wd, bd, ws, out);
}

// Round 7
// 209.892 us; speedup vs baseline: 2.6331x; 1.0607x over previous
//
#include <hip/hip_runtime.h>
#include <hip/hip_bf16.h>
#include <stdint.h>

#define B_ 4
#define T_ 8
#define N_ 4096
#define F_ 32
#define BT_ (B_*T_)
#define ROWS_ (B_*N_)
#define CAP_ 128
#define EPS_ 1e-5f
#define NELEM_ (B_*T_*N_*F_)

// ---- workspace layout (float offsets) ----
#define WS_BNP    0                       // 256 * 64 partials
#define WS_ROWSUM 16384                   // 4096
#define WS_DEG    (WS_ROWSUM + 4096)      // 4096 (int)
#define WS_FRG    (WS_DEG + 4096)         // 52 frags * 64 lanes * 4 dwords
#define WS_PAIR   (WS_FRG + 52*256)       // 4096*CAP_*2  (idx*F_ as float-bits, val)
#define WS_XA     (WS_PAIR + 4096*CAP_*2) // BT_*N_*F_

typedef float v4f __attribute__((ext_vector_type(4)));
typedef _Float16 half8 __attribute__((ext_vector_type(8)));
union HU { uint32_t u[4]; half8 v; };

__device__ inline float sigm_f(float x) {
  return __builtin_amdgcn_rcpf(1.0f + __expf(-x));
}
__device__ inline uint32_t f16pair(float a, float b) {
  union { _Float16 h; unsigned short s; } x, y;
  x.h = (_Float16)a; y.h = (_Float16)b;
  return (uint32_t)x.s | ((uint32_t)y.s << 16);
}
__device__ inline void sp2(float a0, float a1, uint32_t& hi, uint32_t& lo) {
  _Float16 h0 = (_Float16)a0, h1 = (_Float16)a1;
  float r0 = a0 - (float)h0, r1 = a1 - (float)h1;
  union { _Float16 h; unsigned short s; } u0, u1, v0, v1;
  u0.h = h0; u1.h = h1; v0.h = (_Float16)r0; v1.h = (_Float16)r1;
  hi = (uint32_t)u0.s | ((uint32_t)u1.s << 16);
  lo = (uint32_t)v0.s | ((uint32_t)v1.s << 16);
}

// ---- K1: merged CSR build (blocks 0..4095) + BN partial stats (4096..4351) ----
__global__ void __launch_bounds__(256)
k_pre(const float* __restrict__ x, const float* __restrict__ A, float* __restrict__ ws) {
  if (blockIdx.x < 4096) {
    int m = blockIdx.x;
    __shared__ int cnt;
    __shared__ float rsum[256];
    if (threadIdx.x == 0) cnt = 0;
    __syncthreads();
    int* deg = (int*)&ws[WS_DEG];
    float2* pair = (float2*)&ws[WS_PAIR];
    const float4* A4 = (const float4*)(A + (size_t)m * N_);
    float4 av4[4];
#pragma unroll
    for (int i = 0; i < 4; i++) av4[i] = A4[threadIdx.x + 256 * i];   // 4 loads in flight
    float lsum = 0.f;
#pragma unroll
    for (int i = 0; i < 4; i++) {
      float av[4] = {av4[i].x, av4[i].y, av4[i].z, av4[i].w};
      int nb4 = (threadIdx.x + 256 * i) * 4;
#pragma unroll
      for (int r = 0; r < 4; r++) {
        float a = av[r];
        if (a != 0.0f) {
          int p = atomicAdd(&cnt, 1);
          if (p < CAP_) pair[(size_t)m * CAP_ + p] = make_float2(__int_as_float((nb4 + r) * F_), a);
          lsum += a;
        }
      }
    }
    rsum[threadIdx.x] = lsum;
    __syncthreads();
    int c = cnt;
    for (int p = c + threadIdx.x; p < 64; p += 256)
      pair[(size_t)m * CAP_ + p] = make_float2(__int_as_float(0), 0.0f);
    for (int s = 128; s > 0; s >>= 1) {
      if (threadIdx.x < s) rsum[threadIdx.x] += rsum[threadIdx.x + s];
      __syncthreads();
    }
    if (threadIdx.x == 0) { deg[m] = min(c, CAP_); ws[WS_ROWSUM + m] = rsum[0]; }
  } else {
    int bnb = blockIdx.x - 4096;
    const float4* x4 = (const float4*)x;
    int tid = bnb * 256 + threadIdx.x;
    float s[4] = {0,0,0,0}, s2[4] = {0,0,0,0};
    for (int i = tid; i < NELEM_ / 4; i += 256 * 256) {
      float4 v = x4[i];
      s[0] += v.x; s2[0] += v.x * v.x;
      s[1] += v.y; s2[1] += v.y * v.y;
      s[2] += v.z; s2[2] += v.z * v.z;
      s[3] += v.w; s2[3] += v.w * v.w;
    }
    __shared__ float ls[256][4], ls2[256][4];
#pragma unroll
    for (int r = 0; r < 4; r++) { ls[threadIdx.x][r] = s[r]; ls2[threadIdx.x][r] = s2[r]; }
    __syncthreads();
    int t = threadIdx.x;
    if (t < 32) {
      int g = t >> 2, r = t & 3;
      float a = 0.f;
      for (int q = g; q < 256; q += 8) a += ls[q][r];
      ws[WS_BNP + bnb * 64 + t] = a;
    } else if (t < 64) {
      int cch = t - 32;
      int g = cch >> 2, r = cch & 3;
      float b2 = 0.f;
      for (int q = g; q < 256; q += 8) b2 += ls2[q][r];
      ws[WS_BNP + bnb * 64 + t] = b2;
    }
  }
}

// ---- K2: sparse aggregation (blocks 0..1023) + weight-fragment fold (block 1024) ----
// agg block: 32 rows x 8 f4-lanes, 4 bt streams. chunk = blockIdx&7 -> XCD-local x slices.
__global__ void __launch_bounds__(256)
k_agg(const float* __restrict__ x,
      const float* __restrict__ gamma, const float* __restrict__ beta,
      const float* __restrict__ Wg, const float* __restrict__ bg,
      const float* __restrict__ Wih, const float* __restrict__ bih,
      const float* __restrict__ Whh, const float* __restrict__ bhh,
      float* __restrict__ ws) {
  __shared__ float sh[6688];
  int tid = threadIdx.x;
  if (blockIdx.x >= 1024) {
    // ---- fold: BN stats + compose W into fp16 A-fragments ----
    float* Wx_s = sh;              // [32][192]
    float* Us_s = sh + 6144;       // [192]
    float* Vs_s = sh + 6336;       // [192]
    float* bns  = sh + 6528;       // [64]
    float* scale_s = sh + 6592;    // [32]
    float* shift_s = sh + 6624;    // [32]
    float* p_s     = sh + 6656;    // [32]
    if (tid < 64) {
      float a = 0.f;
      for (int p = 0; p < 256; p++) a += ws[WS_BNP + p * 64 + tid];
      bns[tid] = a;
    }
    __syncthreads();
    if (tid < 32) {
      float cntf = (float)(B_ * T_ * N_);
      float mean = bns[tid] / cntf;
      float var = bns[32 + tid] / cntf - mean * mean;
      float sc = gamma[tid] * rsqrtf(var + EPS_);
      scale_s[tid] = sc;
      shift_s[tid] = beta[tid] - mean * sc;
    }
    __syncthreads();
    if (tid < 32) {
      float acc = 0.f;
      for (int f = 0; f < 32; f++) acc += shift_s[f] * Wg[f * 32 + tid];
      p_s[tid] = acc;
    }
    __syncthreads();
    for (int e = tid; e < 32 * 192; e += 256) {
      int f = e / 192, j = e % 192;
      float acc = 0.f;
      for (int c = 0; c < 32; c++) acc += Wg[f * 32 + c] * Wih[c * 192 + j];
      Wx_s[e] = scale_s[f] * acc;
    }
    if (tid < 192) {
      float au = 0.f, av = 0.f;
      for (int c = 0; c < 32; c++) { au += p_s[c] * Wih[c * 192 + tid]; av += bg[c] * Wih[c * 192 + tid]; }
      Us_s[tid] = au; Vs_s[tid] = av + bih[tid];
    }
    __syncthreads();
    int w = tid >> 6, L = tid & 63, q = L >> 4, c = L & 15;
    uint32_t* wsu = (uint32_t*)ws;
    for (int fi = w; fi < 52; fi += 4) {
      int mt, kt;
      if (fi < 32)      { mt = fi >> 2;            kt = fi & 3; }
      else if (fi < 40) { mt = 8 + ((fi - 32) >> 1); kt = (fi & 1) ? 3 : 0; }
      else              { int r = fi - 40; mt = 12 + r / 3; kt = 1 + r % 3; }
      int cls = mt >> 2;
      int col = (cls < 2) ? mt * 16 + c : 128 + (mt & 3) * 16 + c;
#pragma unroll
      for (int d = 0; d < 4; d++) {
        float a01[2];
#pragma unroll
        for (int h2 = 0; h2 < 2; h2++) {
          int k = kt * 32 + q * 8 + 2 * d + h2;
          float v;
          if (k < 32)       v = (cls == 3) ? 0.f : Wx_s[k * 192 + col];
          else if (k < 96)  v = (cls == 2) ? 0.f : Whh[(k - 32) * 192 + col];
          else if (k == 96) v = (cls == 3) ? 0.f : Us_s[col];
          else if (k == 97) v = (cls < 2) ? (Vs_s[col] + bhh[col]) : (cls == 2 ? Vs_s[col] : bhh[col]);
          else              v = 0.f;
          a01[h2] = v;
        }
        wsu[WS_FRG + fi * 256 + L * 4 + d] = f16pair(a01[0], a01[1]);
      }
    }
    return;
  }
  // ---- aggregation ----
  float2* pl = (float2*)sh;            // [32][65] padded: row stride 130 dwords
  int chunk = blockIdx.x & 7;          // same chunk -> same XCD (round-robin dispatch)
  int mg = blockIdx.x >> 3;            // [0,128): 32-row group
  int row = tid >> 3, f4 = tid & 7;
  int m = mg * 32 + row;
  const int* deg = (const int*)&ws[WS_DEG];
  const float2* pair = (const float2*)&ws[WS_PAIR];
  for (int qq = tid; qq < 2048; qq += 256) {
    int r = qq >> 6, sl = qq & 63;
    pl[r * 65 + sl] = pair[(size_t)(mg * 32 + r) * CAP_ + sl];
  }
  __syncthreads();
  int d = deg[m];
  int dm = min(d, 64);
  // wave-uniform bound: max over the wave's 8 rows (row bits = lane bits [3:5])
  int bound = dm;
  bound = max(bound, __shfl_xor(bound, 8, 64));
  bound = max(bound, __shfl_xor(bound, 16, 64));
  bound = max(bound, __shfl_xor(bound, 32, 64));
  int bt0 = chunk * 4;
  const float* xb0 = x + (size_t)bt0 * N_ * F_;
  const float* xb1 = xb0 + N_ * F_;
  const float* xb2 = xb1 + N_ * F_;
  const float* xb3 = xb2 + N_ * F_;
  int fo = f4 * 4;
  v4f a0 = {0,0,0,0}, a1 = {0,0,0,0}, a2 = {0,0,0,0}, a3 = {0,0,0,0};
#pragma unroll 2
  for (int k = 0; k < bound; k++) {
    float2 p = pl[row * 65 + k];
    int off = __float_as_int(p.x) + fo;        // idx pre-scaled by F_
    float vv = p.y;
    a0 += vv * *(const v4f*)(xb0 + off);
    a1 += vv * *(const v4f*)(xb1 + off);
    a2 += vv * *(const v4f*)(xb2 + off);
    a3 += vv * *(const v4f*)(xb3 + off);
  }
  if (d > 64) {                                // statistically never (avg deg ~32)
    for (int k = 64; k < d; k++) {
      float2 p = pair[(size_t)m * CAP_ + k];
      int off = __float_as_int(p.x) + fo;
      float vv = p.y;
      a0 += vv * *(const v4f*)(xb0 + off);
      a1 += vv * *(const v4f*)(xb1 + off);
      a2 += vv * *(const v4f*)(xb2 + off);
      a3 += vv * *(const v4f*)(xb3 + off);
    }
  }
  size_t ob = (size_t)bt0 * N_ * F_ + m * F_ + fo;
  *(v4f*)(ws + WS_XA + ob) = a0;
  *(v4f*)(ws + WS_XA + ob + (size_t)N_ * F_) = a1;
  *(v4f*)(ws + WS_XA + ob + (size_t)2 * N_ * F_) = a2;
  *(v4f*)(ws + WS_XA + ob + (size_t)3 * N_ * F_) = a3;
}

// ---- K3: MFMA GRU (unchanged from R6) ----
#define LDA(fi) (*(const half8*)(frg + (fi)*256 + L*4))
#define DO1(mt, fi, BH, BL) { half8 af = LDA(fi); \
  acc[mt] = __builtin_amdgcn_mfma_f32_16x16x32_f16(af, BH, acc[mt], 0, 0, 0); \
  acc[mt] = __builtin_amdgcn_mfma_f32_16x16x32_f16(af, BL, acc[mt], 0, 0, 0); }

__global__ void __launch_bounds__(256, 1)
k_gru(const float* __restrict__ Wd, const float* __restrict__ bd,
      const float* __restrict__ ws, float* __restrict__ out) {
  __shared__ uint32_t frg[52 * 256];
  __shared__ uint32_t hx[4 * 1344];
  {
    const uint4* gf = (const uint4*)(ws + WS_FRG);
    uint4* sf = (uint4*)frg;
    for (int i = threadIdx.x; i < 52 * 64; i += 256) sf[i] = gf[i];
  }
  __syncthreads();
  int wid = threadIdx.x >> 6, L = threadIdx.x & 63;
  int q = L >> 4, c = L & 15;
  uint32_t* hxw = hx + wid * 1344;
  int row0 = blockIdx.x * 64 + wid * 16;
  int b = row0 >> 12;
  int nb = row0 & (N_ - 1);
  float wdv[4][4];
#pragma unroll
  for (int g = 0; g < 4; g++)
#pragma unroll
    for (int r = 0; r < 4; r++) wdv[g][r] = Wd[16 * g + 4 * q + r];
  float bdv = bd[0];
  HU b3h, b3l;
#pragma unroll
  for (int d = 0; d < 4; d++) { b3h.u[d] = 0; b3l.u[d] = 0; }
  {
    float rsv = ws[WS_ROWSUM + nb + c];
    uint32_t rhi, rlo;
    sp2(rsv, 1.0f, rhi, rlo);
    if (q == 0) { b3h.u[0] = rhi; b3l.u[0] = rlo & 0xFFFFu; }
  }
  float h[4][4];
#pragma unroll
  for (int g = 0; g < 4; g++)
#pragma unroll
    for (int r = 0; r < 4; r++) h[g][r] = 0.f;

  const float* xab = ws + WS_XA;
  size_t xo0 = ((size_t)(b * T_) * N_ + nb + c) * F_ + q * 8;
  float4 xaA = *(const float4*)(xab + xo0);
  float4 xaB = *(const float4*)(xab + xo0 + 4);

  for (int t = 0; t < T_; t++) {
    float4 nxA, nxB;
    if (t < T_ - 1) {
      size_t xo = ((size_t)(b * T_ + t + 1) * N_ + nb + c) * F_ + q * 8;
      nxA = *(const float4*)(xab + xo);
      nxB = *(const float4*)(xab + xo + 4);
    }
#pragma unroll
    for (int g = 0; g < 4; g++)
#pragma unroll
      for (int rp = 0; rp < 2; rp++) {
        uint32_t phi, plo;
        sp2(h[g][2 * rp], h[g][2 * rp + 1], phi, plo);
        int pidx = 8 * g + 2 * q + rp;
        hxw[(pidx * 2 + 0) * 21 + c] = phi;
        hxw[(pidx * 2 + 1) * 21 + c] = plo;
      }
    HU b1h, b1l, b2h, b2l;
#pragma unroll
    for (int d = 0; d < 4; d++) {
      b1h.u[d] = hxw[((4 * q + d) * 2 + 0) * 21 + c];
      b1l.u[d] = hxw[((4 * q + d) * 2 + 1) * 21 + c];
      b2h.u[d] = hxw[((16 + 4 * q + d) * 2 + 0) * 21 + c];
      b2l.u[d] = hxw[((16 + 4 * q + d) * 2 + 1) * 21 + c];
    }
    v4f acc[16];
#pragma unroll
    for (int i = 0; i < 16; i++) acc[i] = (v4f){0.f, 0.f, 0.f, 0.f};
    DO1(0,1,b1h.v,b1l.v)  DO1(1,5,b1h.v,b1l.v)  DO1(2,9,b1h.v,b1l.v)  DO1(3,13,b1h.v,b1l.v)
    DO1(4,17,b1h.v,b1l.v) DO1(5,21,b1h.v,b1l.v) DO1(6,25,b1h.v,b1l.v) DO1(7,29,b1h.v,b1l.v)
    DO1(12,40,b1h.v,b1l.v) DO1(13,43,b1h.v,b1l.v) DO1(14,46,b1h.v,b1l.v) DO1(15,49,b1h.v,b1l.v)
    DO1(0,2,b2h.v,b2l.v)  DO1(1,6,b2h.v,b2l.v)  DO1(2,10,b2h.v,b2l.v) DO1(3,14,b2h.v,b2l.v)
    DO1(4,18,b2h.v,b2l.v) DO1(5,22,b2h.v,b2l.v) DO1(6,26,b2h.v,b2l.v) DO1(7,30,b2h.v,b2l.v)
    DO1(12,41,b2h.v,b2l.v) DO1(13,44,b2h.v,b2l.v) DO1(14,47,b2h.v,b2l.v) DO1(15,50,b2h.v,b2l.v)
    DO1(0,3,b3h.v,b3l.v)  DO1(1,7,b3h.v,b3l.v)  DO1(2,11,b3h.v,b3l.v) DO1(3,15,b3h.v,b3l.v)
    DO1(4,19,b3h.v,b3l.v) DO1(5,23,b3h.v,b3l.v) DO1(6,27,b3h.v,b3l.v) DO1(7,31,b3h.v,b3l.v)
    DO1(8,33,b3h.v,b3l.v) DO1(9,35,b3h.v,b3l.v) DO1(10,37,b3h.v,b3l.v) DO1(11,39,b3h.v,b3l.v)
    DO1(12,42,b3h.v,b3l.v) DO1(13,45,b3h.v,b3l.v) DO1(14,48,b3h.v,b3l.v) DO1(15,51,b3h.v,b3l.v)
    HU b0h, b0l;
    sp2(xaA.x, xaA.y, b0h.u[0], b0l.u[0]);
    sp2(xaA.z, xaA.w, b0h.u[1], b0l.u[1]);
    sp2(xaB.x, xaB.y, b0h.u[2], b0l.u[2]);
    sp2(xaB.z, xaB.w, b0h.u[3], b0l.u[3]);
    DO1(0,0,b0h.v,b0l.v)  DO1(1,4,b0h.v,b0l.v)  DO1(2,8,b0h.v,b0l.v)  DO1(3,12,b0h.v,b0l.v)
    DO1(4,16,b0h.v,b0l.v) DO1(5,20,b0h.v,b0l.v) DO1(6,24,b0h.v,b0l.v) DO1(7,28,b0h.v,b0l.v)
    DO1(8,32,b0h.v,b0l.v) DO1(9,34,b0h.v,b0l.v) DO1(10,36,b0h.v,b0l.v) DO1(11,38,b0h.v,b0l.v)
    float o = 0.f;
#pragma unroll
    for (int g = 0; g < 4; g++)
#pragma unroll
      for (int r = 0; r < 4; r++) {
        float rr = sigm_f(acc[g][r]);
        float z  = sigm_f(acc[4 + g][r]);
        float nn = 2.0f * sigm_f(2.0f * (acc[8 + g][r] + rr * acc[12 + g][r])) - 1.0f;
        float hn = z * (h[g][r] - nn) + nn;
        h[g][r] = hn;
        o += wdv[g][r] * hn;
      }
    o += __shfl_xor(o, 16, 64);
    o += __shfl_xor(o, 32, 64);
    if (L < 16) out[(size_t)(b * T_ + t) * N_ + nb + L] = o + bdv;
    xaA = nxA; xaB = nxB;
  }
}

extern "C" void kernel_launch(void* const* d_in, const int* in_sizes, int n_in,
                              void* d_out, int out_size, void* d_ws, size_t ws_size,
                              hipStream_t stream) {
  const float* x     = (const float*)d_in[0];
  const float* adj   = (const float*)d_in[1];
  const float* gamma = (const float*)d_in[2];
  const float* beta  = (const float*)d_in[3];
  const float* Wg    = (const float*)d_in[4];
  const float* bg    = (const float*)d_in[5];
  const float* Wih   = (const float*)d_in[6];
  const float* Whh   = (const float*)d_in[7];
  const float* bih   = (const float*)d_in[8];
  const float* bhh   = (const float*)d_in[9];
  const float* Wd    = (const float*)d_in[10];
  const float* bd    = (const float*)d_in[11];
  float* ws = (float*)d_ws;
  float* out = (float*)d_out;

  k_pre<<<4096 + 256, 256, 0, stream>>>(x, adj, ws);
  k_agg<<<1024 + 1, 256, 0, stream>>>(x, gamma, beta, Wg, bg, Wih, bih, Whh, bhh, ws);
  k_gru<<<256, 256, 0, stream>>>(Wd, bd, ws, out);
}